// Round 8
// baseline (5546.262 us; speedup 1.0000x reference)
//
#include <hip/hip_runtime.h>
#include <cstddef>
#include <cstdint>

// ---------------- problem dims ----------------
#define T_ 32
#define A_ 32
#define F_ 4
#define E_ 256
#define FE_ 1024
#define H_ 768
#define H2_ 1536
#define G4_ 3072     // 4*H
#define G8_ 6144     // 4*H2
#define DTOK_ 256
#define DDEC_ 1280
#define SEQ_ 1024    // T*A

typedef unsigned long long ull;

// ---------------- ws layout (float offsets) ----------------
constexpr size_t OFF_PACKED  = 0;                          // 1024*1024
constexpr size_t OFF_XF      = OFF_PACKED + 1024ull*1024;  // 1024*3072 (swizzled)
constexpr size_t OFF_XB      = OFF_XF + 1024ull*3072;
constexpr size_t OFF_XD      = OFF_XB + 1024ull*3072;      // 32*6144 (swizzled)
constexpr size_t OFF_XDIN    = OFF_XD + 32*6144;           // 32*1280
constexpr size_t OFF_ENC     = OFF_XDIN + 32*1280;         // 1024*1536
constexpr size_t OFF_HN      = OFF_ENC + 1024ull*1536;     // 32*1536
constexpr size_t OFF_AMAT    = OFF_HN + 32*1536;           // 32*1536
constexpr size_t OFF_C0      = OFF_AMAT + 32*1536;         // 1536 (no memset)
// memset region: flags + decoder pairs
constexpr size_t OFF_FLAGS   = OFF_C0 + 1536;              // 128 ints (64 fwd, 64 bwd)
constexpr size_t OFF_PAIRS_D = OFF_FLAGS + 128;            // dec [par][1536] u64 = 6144 f
constexpr size_t MEMSET_BYTES = (128 + 6144) * 4;          // 25088
// write-once h history (no memset needed)
constexpr size_t OFF_HISTF   = OFF_PAIRS_D + 6144;         // 1024*768
constexpr size_t OFF_HISTB   = OFF_HISTF + 1024ull*768;    // 1024*768

__device__ __forceinline__ float sigf(float x) { return 1.f / (1.f + __expf(-x)); }

__device__ __forceinline__ ull ld_agent(const ull* p) {
    return __hip_atomic_load(p, __ATOMIC_RELAXED, __HIP_MEMORY_SCOPE_AGENT);
}
__device__ __forceinline__ void st_agent(ull* p, ull v) {
    __hip_atomic_store(p, v, __ATOMIC_RELAXED, __HIP_MEMORY_SCOPE_AGENT);
}
__device__ __forceinline__ int ld_agent_i(const int* p) {
    return __hip_atomic_load(p, __ATOMIC_RELAXED, __HIP_MEMORY_SCOPE_AGENT);
}
__device__ __forceinline__ void st_agent_f(float* p, float v) {
    __hip_atomic_store(p, v, __ATOMIC_RELAXED, __HIP_MEMORY_SCOPE_AGENT);
}

// ---------------- embed + decoder-input gather ----------------
__global__ void embed_k(const int* __restrict__ lattice, const int* __restrict__ inputs,
                        const int* __restrict__ gold, const int* __restrict__ sos,
                        const float* __restrict__ emb, const float* __restrict__ tok_emb,
                        float* __restrict__ packed, float* __restrict__ xdec_in) {
    int b = blockIdx.x, tid = threadIdx.x;
    if (b < SEQ_) {
        #pragma unroll
        for (int f = 0; f < F_; ++f) {
            int vid = lattice[b * F_ + f];
            packed[(size_t)b * FE_ + f * E_ + tid] = emb[(size_t)vid * E_ + tid];
        }
    } else {
        int t = b - SEQ_;  // 0..31
        for (int j = tid; j < DDEC_; j += 256) {
            float v;
            if (j < FE_) {
                int f = j >> 8, e2 = j & 255;
                int vid = (t == 0) ? sos[f]
                                   : lattice[(((t - 1) * A_) + gold[t - 1]) * F_ + f];
                v = emb[(size_t)vid * E_ + e2];
            } else {
                v = tok_emb[(size_t)inputs[t] * DTOK_ + (j - FE_)];
            }
            xdec_in[(size_t)t * DDEC_ + j] = v;
        }
    }
}

// ---------------- fp32 tiled GEMM: C[M,N] = A[M,K] @ B[K,N] + bias ----------------
// swh != 0: gate-interleaved output swizzle for the LSTM consumers:
//   n = q*swh + j  -> n' = (j/dbs)*(4*dbs) + (j%dbs)*4 + q.  (q tile-uniform: swh%BN==0)
#define BM 128
#define BN 128
#define BK 8
__device__ __forceinline__ void gemm_body(
    const float* __restrict__ A, const float* __restrict__ B,
    const float* __restrict__ bias, float* __restrict__ C,
    int M, int N, int K, int n0, int m0, int swh, int dbs) {
    __shared__ float As[BK][BM + 4];
    __shared__ float Bs[BK][BN + 4];
    int tid = threadIdx.x;
    int tx = tid & 15, ty = tid >> 4;
    int lam = tid >> 1, lak = (tid & 1) * 4;
    int lbk = tid >> 5, lbn = (tid & 31) * 4;
    float acc[8][8] = {};
    for (int k0 = 0; k0 < K; k0 += BK) {
        float4 av = make_float4(0.f, 0.f, 0.f, 0.f);
        if (m0 + lam < M)
            av = *(const float4*)(A + (size_t)(m0 + lam) * K + k0 + lak);
        float4 bv = *(const float4*)(B + (size_t)(k0 + lbk) * N + n0 + lbn);
        __syncthreads();
        As[lak + 0][lam] = av.x; As[lak + 1][lam] = av.y;
        As[lak + 2][lam] = av.z; As[lak + 3][lam] = av.w;
        *(float4*)&Bs[lbk][lbn] = bv;
        __syncthreads();
        #pragma unroll
        for (int kk = 0; kk < BK; ++kk) {
            float a[8], b[8];
            *(float4*)&a[0] = *(const float4*)&As[kk][ty * 8];
            *(float4*)&a[4] = *(const float4*)&As[kk][ty * 8 + 4];
            *(float4*)&b[0] = *(const float4*)&Bs[kk][tx * 8];
            *(float4*)&b[4] = *(const float4*)&Bs[kk][tx * 8 + 4];
            #pragma unroll
            for (int i = 0; i < 8; ++i)
                #pragma unroll
                for (int j = 0; j < 8; ++j)
                    acc[i][j] += a[i] * b[j];
        }
    }
    int qg = 0, jb = 0;
    if (swh) { qg = n0 / swh; jb = n0 - qg * swh; }
    #pragma unroll
    for (int i = 0; i < 8; ++i) {
        int m = m0 + ty * 8 + i;
        if (m >= M) break;
        #pragma unroll
        for (int j = 0; j < 8; ++j) {
            int n = n0 + tx * 8 + j;
            float bb = bias ? bias[n] : 0.f;
            float v = acc[i][j] + bb;
            if (swh) {
                int jc = jb + tx * 8 + j;
                n = (jc / dbs) * (4 * dbs) + (jc % dbs) * 4 + qg;
            }
            C[(size_t)m * N + n] = v;
        }
    }
}

__global__ __launch_bounds__(256) void gemm_bias_k(
    const float* __restrict__ A, const float* __restrict__ B,
    const float* __restrict__ bias, float* __restrict__ C,
    int M, int N, int K, int swh, int dbs) {
    gemm_body(A, B, bias, C, M, N, K, blockIdx.x * BN, blockIdx.y * BM, swh, dbs);
}

__global__ __launch_bounds__(256) void gemm_bias2_k(
    const float* __restrict__ A,
    const float* __restrict__ B0, const float* __restrict__ bias0, float* __restrict__ C0,
    const float* __restrict__ B1, const float* __restrict__ bias1, float* __restrict__ C1,
    int M, int N, int K, int swh, int dbs) {
    const float* B = blockIdx.z ? B1 : B0;
    const float* bias = blockIdx.z ? bias1 : bias0;
    float* C = blockIdx.z ? C1 : C0;
    gemm_body(A, B, bias, C, M, N, K, blockIdx.x * BN, blockIdx.y * BM, swh, dbs);
}

// ---------------- persistent encoder LSTM (fwd + bwd) ----------------
// r2 topology (best measured): 128 blocks ([0,64) fwd, [64,128) bwd), 768 thr,
// out=tid>>4 (48 gate sums), kl=tid&15 (16-way K-split, 48 w/thread).
// NEW sync fabric: per-producer-block flags (64/dir, polled by wave0 1:1 -> 48x
// less MALL poll traffic than per-value tags) + write-once h history hist[t][768]
// read via plain coalesced loads at fresh addresses (no L1/L2 staleness possible,
// no parity, no WAR). Producer: 12-lane coalesced agent h stores -> barrier
// (drains vmem) -> single release flag store (r1-proven ordering).
__global__ __launch_bounds__(768, 1) void lstm_enc_k(
    const float* __restrict__ Xf, const float* __restrict__ Xb,
    const float* __restrict__ Whf, const float* __restrict__ Whb,
    float* __restrict__ enc, float* __restrict__ histF, float* __restrict__ histB,
    int* __restrict__ flagsE, ull* __restrict__ pairsD, float* __restrict__ c0) {
    const int dir = blockIdx.x >> 6;
    const int wb  = blockIdx.x & 63;
    const float* X  = dir ? Xb : Xf;
    const float* Wh = dir ? Whb : Whf;
    float* hist = dir ? histB : histF;
    int* flg = flagsE + dir * 64;
    const int tid = threadIdx.x;
    const int out = tid >> 4, kl = tid & 15;
    const int q = out / 12, jj = out - q * 12;
    const int col = q * H_ + wb * 12 + jj;

    float w[12][4];
    #pragma unroll
    for (int i = 0; i < 12; ++i) {
        int kb = kl * 4 + 64 * i;
        #pragma unroll
        for (int e = 0; e < 4; ++e)
            w[i][e] = Wh[(size_t)(kb + e) * G4_ + col];
    }

    __shared__ float h_s[768];
    __shared__ float gbuf[48];
    __shared__ float xs[48];
    float c = 0.f;

    for (int t = 0; t < SEQ_; ++t) {
        const int row = dir ? (SEQ_ - 1 - t) : t;
        float xv = 0.f;
        if (tid < 48) xv = X[(size_t)row * G4_ + wb * 48 + tid];  // swizzled, prefetch

        if (t > 0 && tid < 64) {
            while (ld_agent_i(&flg[tid]) < t) {}
        }
        __syncthreads();                                  // A1: flags passed
        h_s[tid] = (t == 0) ? 0.f : hist[(size_t)(t - 1) * 768 + tid];
        __syncthreads();                                  // A2: h_s ready

        float s = 0.f;
        #pragma unroll
        for (int i = 0; i < 12; ++i) {
            const float4 hv = *(const float4*)&h_s[kl * 4 + 64 * i];
            s += w[i][0] * hv.x + w[i][1] * hv.y + w[i][2] * hv.z + w[i][3] * hv.w;
        }
        s += __shfl_xor(s, 1); s += __shfl_xor(s, 2);
        s += __shfl_xor(s, 4); s += __shfl_xor(s, 8);
        if (kl == 0) gbuf[out] = s;
        if (tid < 48) xs[tid] = xv;
        __syncthreads();                                  // B: gbuf/xs ready

        if (tid < 12) {
            // xs swizzle order: jj*4 + gate
            float iv = gbuf[tid]      + xs[4 * tid + 0];
            float fv = gbuf[12 + tid] + xs[4 * tid + 1];
            float gv = gbuf[24 + tid] + xs[4 * tid + 2];
            float ov = gbuf[36 + tid] + xs[4 * tid + 3];
            c = sigf(fv) * c + sigf(iv) * tanhf(gv);
            float h = sigf(ov) * tanhf(c);
            int jg = wb * 12 + tid;
            enc[(size_t)row * H2_ + dir * H_ + jg] = h;
            st_agent_f(&hist[(size_t)t * 768 + jg], h);   // write-once history
            if (t == SEQ_ - 1) {
                st_agent(pairsD + (size_t)(dir * H_ + jg),
                         (ull)__float_as_uint(h));        // tag 0 seed for decoder
                c0[dir * H_ + jg] = c;
            }
        }
        __syncthreads();                                  // C: all stores drained
        if (tid == 0)
            __hip_atomic_store(&flg[wb], t + 1, __ATOMIC_RELEASE, __HIP_MEMORY_SCOPE_AGENT);
    }
}

// ---------------- persistent decoder LSTM (r6 verbatim, proven) ----------------
__global__ __launch_bounds__(768, 1) void lstm_dec_k(
    const float* __restrict__ Xd, const float* __restrict__ Wh,
    float* __restrict__ Hn, ull* __restrict__ pairs,
    const float* __restrict__ c0) {
    const int wb = blockIdx.x;
    const int tid = threadIdx.x;
    const int w = tid >> 6, lane = tid & 63;
    const int g16 = lane >> 4;
    const int jg = wb * 12 + w;
    const int d = lane >> 2, q = lane & 3;

    float wgt[6][4][4];
    #pragma unroll
    for (int i = 0; i < 6; ++i)
        #pragma unroll
        for (int e = 0; e < 4; ++e) {
            int k = 4 * lane + e + 256 * i;
            #pragma unroll
            for (int g = 0; g < 4; ++g)
                wgt[i][e][g] = Wh[(size_t)k * G8_ + g * H2_ + jg];
        }
    #pragma unroll
    for (int i = 0; i < 6; ++i)
        #pragma unroll
        for (int e = 0; e < 4; ++e)
            #pragma unroll
            for (int g = 0; g < 4; ++g)
                asm volatile("" : "+v"(wgt[i][e][g]));

    __shared__ float h_s[2][1536];
    __shared__ float part[4][64];
    float c = (w == 0 && lane < 48) ? c0[wb * 12 + d] : 0.f;

    for (int t = 0; t < T_; ++t) {
        float xq = 0.f;
        if (w == 0 && lane < 48) xq = Xd[(size_t)t * G8_ + wb * 48 + lane];

        const int par = t & 1;
        ull* p0 = pairs + (size_t)par * 1536 + tid;
        ull* p1 = p0 + 768;
        ull v0 = ld_agent(p0);
        while ((unsigned)(v0 >> 32) != (unsigned)t) v0 = ld_agent(p0);
        ull v1 = ld_agent(p1);
        while ((unsigned)(v1 >> 32) != (unsigned)t) v1 = ld_agent(p1);
        h_s[par][tid]       = __uint_as_float((unsigned)v0);
        h_s[par][tid + 768] = __uint_as_float((unsigned)v1);
        __syncthreads();                                   // A

        float a0 = 0.f, a1 = 0.f, a2 = 0.f, a3 = 0.f;
        #pragma unroll
        for (int i = 0; i < 6; ++i) {
            const float4 hv = *(const float4*)&h_s[par][4 * lane + 256 * i];
            a0 += wgt[i][0][0] * hv.x + wgt[i][1][0] * hv.y + wgt[i][2][0] * hv.z + wgt[i][3][0] * hv.w;
            a1 += wgt[i][0][1] * hv.x + wgt[i][1][1] * hv.y + wgt[i][2][1] * hv.z + wgt[i][3][1] * hv.w;
            a2 += wgt[i][0][2] * hv.x + wgt[i][1][2] * hv.y + wgt[i][2][2] * hv.z + wgt[i][3][2] * hv.w;
            a3 += wgt[i][0][3] * hv.x + wgt[i][1][3] * hv.y + wgt[i][2][3] * hv.z + wgt[i][3][3] * hv.w;
        }
        #pragma unroll
        for (int m = 1; m < 16; m <<= 1) {
            a0 += __shfl_xor(a0, m); a1 += __shfl_xor(a1, m);
            a2 += __shfl_xor(a2, m); a3 += __shfl_xor(a3, m);
        }
        if ((lane & 15) == 0)
            *(float4*)&part[g16][w * 4] = make_float4(a0, a1, a2, a3);
        __syncthreads();                                   // B

        if (w == 0) {
            float s = part[0][lane] + part[1][lane] + part[2][lane] + part[3][lane] + xq;
            float tr = (q == 2) ? tanhf(s) : sigf(s);
            float s1 = __shfl_xor(tr, 1), s2 = __shfl_xor(tr, 2), s3 = __shfl_xor(tr, 3);
            float I  = (q == 0) ? tr : (q == 1) ? s1 : (q == 2) ? s2 : s3;
            float Fv = (q == 0) ? s1 : (q == 1) ? tr : (q == 2) ? s3 : s2;
            float G  = (q == 0) ? s2 : (q == 1) ? s3 : (q == 2) ? tr : s1;
            float O  = (q == 0) ? s3 : (q == 1) ? s2 : (q == 2) ? s1 : tr;
            c = Fv * c + I * G;
            float h = O * tanhf(c);
            float hc = __shfl(h, lane * 4);
            if (lane < 12) {
                Hn[(size_t)t * H2_ + wb * 12 + lane] = hc;
                ull pk = ((ull)(unsigned)(t + 1) << 32) | (ull)__float_as_uint(hc);
                st_agent(pairs + (size_t)((t + 1) & 1) * 1536 + wb * 12 + lane, pk);
            }
        }
    }
}

// ---------------- scores: out[t][a] = Amat[t] . enc[t*32+a] ----------------
__global__ void score_k(const float* __restrict__ Amat, const float* __restrict__ enc,
                        float* __restrict__ outp) {
    int t = blockIdx.x, tid = threadIdx.x;
    __shared__ float a_s[H2_];
    for (int i = tid; i < H2_; i += 256) a_s[i] = Amat[(size_t)t * H2_ + i];
    __syncthreads();
    int aa = tid >> 3, p = tid & 7;
    const float4* e = (const float4*)(enc + (size_t)(t * A_ + aa) * H2_ + p * 192);
    const float4* ap = (const float4*)(a_s + p * 192);
    float s = 0.f;
    #pragma unroll
    for (int i = 0; i < 48; ++i) {
        float4 av = ap[i], ev = e[i];
        s += av.x * ev.x + av.y * ev.y + av.z * ev.z + av.w * ev.w;
    }
    s += __shfl_xor(s, 1); s += __shfl_xor(s, 2); s += __shfl_xor(s, 4);
    if (p == 0) outp[t * A_ + aa] = s;
}

// ---------------- host launch ----------------
extern "C" void kernel_launch(void* const* d_in, const int* in_sizes, int n_in,
                              void* d_out, int out_size, void* d_ws, size_t ws_size,
                              hipStream_t stream) {
    const int*   lattice = (const int*)d_in[0];
    const int*   inputs  = (const int*)d_in[2];
    const int*   gold    = (const int*)d_in[4];
    const int*   sos     = (const int*)d_in[5];
    const float* emb     = (const float*)d_in[6];
    const float* tok     = (const float*)d_in[7];
    const float* Wxf = (const float*)d_in[8];
    const float* Whf = (const float*)d_in[9];
    const float* bf  = (const float*)d_in[10];
    const float* Wxb = (const float*)d_in[11];
    const float* Whb = (const float*)d_in[12];
    const float* bb  = (const float*)d_in[13];
    const float* dWx = (const float*)d_in[14];
    const float* dWh = (const float*)d_in[15];
    const float* db  = (const float*)d_in[16];
    const float* aW  = (const float*)d_in[17];
    float* ws  = (float*)d_ws;
    float* out = (float*)d_out;

    float* packed = ws + OFF_PACKED;
    float* Xf     = ws + OFF_XF;
    float* Xb     = ws + OFF_XB;
    float* Xd     = ws + OFF_XD;
    float* xdin   = ws + OFF_XDIN;
    float* enc    = ws + OFF_ENC;
    float* Hn     = ws + OFF_HN;
    float* Amat   = ws + OFF_AMAT;
    float* c0     = ws + OFF_C0;
    int*   flagsE = (int*)(ws + OFF_FLAGS);
    ull*   pairsD = (ull*)(ws + OFF_PAIRS_D);
    float* histF  = ws + OFF_HISTF;
    float* histB  = ws + OFF_HISTB;

    // reset flags + decoder pair tags (graph-replay safe; hist is write-once,
    // gated by flags, so it needs no reset)
    hipMemsetAsync((char*)d_ws + OFF_FLAGS * sizeof(float), 0, MEMSET_BYTES, stream);

    embed_k<<<SEQ_ + T_, 256, 0, stream>>>(lattice, inputs, gold, sos, emb, tok,
                                           packed, xdin);
    gemm_bias2_k<<<dim3(G4_ / BN, SEQ_ / BM, 2), 256, 0, stream>>>(
        packed, Wxf, bf, Xf, Wxb, bb, Xb, SEQ_, G4_, FE_, H_, 12);
    gemm_bias_k<<<dim3(G8_ / BN, 1), 256, 0, stream>>>(xdin, dWx, db, Xd,
                                                       T_, G8_, DDEC_, H2_, 12);
    lstm_enc_k<<<128, 768, 0, stream>>>(Xf, Xb, Whf, Whb, enc, histF, histB,
                                        flagsE, pairsD, c0);
    lstm_dec_k<<<128, 768, 0, stream>>>(Xd, dWh, Hn, pairsD, c0);
    gemm_bias_k<<<dim3(H2_ / BN, 1), 256, 0, stream>>>(Hn, aW, nullptr, Amat,
                                                       T_, H2_, H2_, 0, 1);
    score_k<<<T_, 256, 0, stream>>>(Amat, enc, out);
}

// Round 9
// 3885.495 us; speedup vs baseline: 1.4274x; 1.4274x over previous
//
#include <hip/hip_runtime.h>
#include <cstddef>
#include <cstdint>

// ---------------- problem dims ----------------
#define T_ 32
#define A_ 32
#define F_ 4
#define E_ 256
#define FE_ 1024
#define H_ 768
#define H2_ 1536
#define G4_ 3072     // 4*H
#define G8_ 6144     // 4*H2
#define DTOK_ 256
#define DDEC_ 1280
#define SEQ_ 1024    // T*A

typedef unsigned long long ull;

// ---------------- ws layout (float offsets) ----------------
constexpr size_t OFF_PACKED  = 0;                          // 1024*1024
constexpr size_t OFF_XF      = OFF_PACKED + 1024ull*1024;  // 1024*3072 (swizzled)
constexpr size_t OFF_XB      = OFF_XF + 1024ull*3072;
constexpr size_t OFF_XD      = OFF_XB + 1024ull*3072;      // 32*6144 (swizzled)
constexpr size_t OFF_XDIN    = OFF_XD + 32*6144;           // 32*1280
constexpr size_t OFF_ENC     = OFF_XDIN + 32*1280;         // 1024*1536
constexpr size_t OFF_HN      = OFF_ENC + 1024ull*1536;     // 32*1536
constexpr size_t OFF_AMAT    = OFF_HN + 32*1536;           // 32*1536
constexpr size_t OFF_C0      = OFF_AMAT + 32*1536;         // 1536 (no memset)
// memset region: X-tile flags + encoder pairs + decoder pairs
constexpr size_t OFF_XFLAGS  = OFF_C0 + 1536;              // 64 ints [dir][rowBlk32]
constexpr size_t OFF_PAIRS_E = OFF_XFLAGS + 64;            // [dir][par][768] u64 = 6144 f
constexpr size_t OFF_PAIRS_D = OFF_PAIRS_E + 6144;         // [par][1536] u64 = 6144 f
constexpr size_t MEMSET_BYTES = (64 + 6144 + 6144) * 4;    // 49408

__device__ __forceinline__ float sigf(float x) { return 1.f / (1.f + __expf(-x)); }

__device__ __forceinline__ ull ld_agent(const ull* p) {
    return __hip_atomic_load(p, __ATOMIC_RELAXED, __HIP_MEMORY_SCOPE_AGENT);
}
__device__ __forceinline__ void st_agent(ull* p, ull v) {
    __hip_atomic_store(p, v, __ATOMIC_RELAXED, __HIP_MEMORY_SCOPE_AGENT);
}
__device__ __forceinline__ void st_agent_f(float* p, float v) {
    __hip_atomic_store(p, v, __ATOMIC_RELAXED, __HIP_MEMORY_SCOPE_AGENT);
}

// ---------------- embed + decoder-input gather ----------------
__global__ void embed_k(const int* __restrict__ lattice, const int* __restrict__ inputs,
                        const int* __restrict__ gold, const int* __restrict__ sos,
                        const float* __restrict__ emb, const float* __restrict__ tok_emb,
                        float* __restrict__ packed, float* __restrict__ xdec_in) {
    int b = blockIdx.x, tid = threadIdx.x;
    if (b < SEQ_) {
        #pragma unroll
        for (int f = 0; f < F_; ++f) {
            int vid = lattice[b * F_ + f];
            packed[(size_t)b * FE_ + f * E_ + tid] = emb[(size_t)vid * E_ + tid];
        }
    } else {
        int t = b - SEQ_;  // 0..31
        for (int j = tid; j < DDEC_; j += 256) {
            float v;
            if (j < FE_) {
                int f = j >> 8, e2 = j & 255;
                int vid = (t == 0) ? sos[f]
                                   : lattice[(((t - 1) * A_) + gold[t - 1]) * F_ + f];
                v = emb[(size_t)vid * E_ + e2];
            } else {
                v = tok_emb[(size_t)inputs[t] * DTOK_ + (j - FE_)];
            }
            xdec_in[(size_t)t * DDEC_ + j] = v;
        }
    }
}

// ---------------- fp32 tiled GEMM (256 thr): C = A@B + bias, optional swizzle ----
// swh != 0: n = q*swh + j -> n' = (j/dbs)*(4*dbs) + (j%dbs)*4 + q  (q tile-uniform)
#define BM 128
#define BN 128
#define BK 8
__device__ __forceinline__ void gemm_body(
    const float* __restrict__ A, const float* __restrict__ B,
    const float* __restrict__ bias, float* __restrict__ C,
    int M, int N, int K, int n0, int m0, int swh, int dbs) {
    __shared__ float As[BK][BM + 4];
    __shared__ float Bs[BK][BN + 4];
    int tid = threadIdx.x;
    int tx = tid & 15, ty = tid >> 4;
    int lam = tid >> 1, lak = (tid & 1) * 4;
    int lbk = tid >> 5, lbn = (tid & 31) * 4;
    float acc[8][8] = {};
    for (int k0 = 0; k0 < K; k0 += BK) {
        float4 av = make_float4(0.f, 0.f, 0.f, 0.f);
        if (m0 + lam < M)
            av = *(const float4*)(A + (size_t)(m0 + lam) * K + k0 + lak);
        float4 bv = *(const float4*)(B + (size_t)(k0 + lbk) * N + n0 + lbn);
        __syncthreads();
        As[lak + 0][lam] = av.x; As[lak + 1][lam] = av.y;
        As[lak + 2][lam] = av.z; As[lak + 3][lam] = av.w;
        *(float4*)&Bs[lbk][lbn] = bv;
        __syncthreads();
        #pragma unroll
        for (int kk = 0; kk < BK; ++kk) {
            float a[8], b[8];
            *(float4*)&a[0] = *(const float4*)&As[kk][ty * 8];
            *(float4*)&a[4] = *(const float4*)&As[kk][ty * 8 + 4];
            *(float4*)&b[0] = *(const float4*)&Bs[kk][tx * 8];
            *(float4*)&b[4] = *(const float4*)&Bs[kk][tx * 8 + 4];
            #pragma unroll
            for (int i = 0; i < 8; ++i)
                #pragma unroll
                for (int j = 0; j < 8; ++j)
                    acc[i][j] += a[i] * b[j];
        }
    }
    int qg = 0, jb = 0;
    if (swh) { qg = n0 / swh; jb = n0 - qg * swh; }
    #pragma unroll
    for (int i = 0; i < 8; ++i) {
        int m = m0 + ty * 8 + i;
        if (m >= M) break;
        #pragma unroll
        for (int j = 0; j < 8; ++j) {
            int n = n0 + tx * 8 + j;
            float bb = bias ? bias[n] : 0.f;
            float v = acc[i][j] + bb;
            if (swh) {
                int jc = jb + tx * 8 + j;
                n = (jc / dbs) * (4 * dbs) + (jc % dbs) * 4 + qg;
            }
            C[(size_t)m * N + n] = v;
        }
    }
}

__global__ __launch_bounds__(256) void gemm_bias_k(
    const float* __restrict__ A, const float* __restrict__ B,
    const float* __restrict__ bias, float* __restrict__ C,
    int M, int N, int K, int swh, int dbs) {
    gemm_body(A, B, bias, C, M, N, K, blockIdx.x * BN, blockIdx.y * BM, swh, dbs);
}

// ---------------- fused encoder + X-GEMM producers ----------------
// 256 blocks x 768 threads (co-resident). Blocks [0,128): r2-structure encoder
// (per-value {tag,h} pair sync, 2.08us/step proven). Blocks [128,256): X-GEMM
// producers; block p computes one 128(M)x384(N)x1024(K) tile of Xf or Xb as
// 4 x (32-row sub-tiles), agent-scope swizzled stores (MALL write-through),
// release-flag per (dir, 32-row block). bwd tiles emit rows descending.
// Encoder gates X reads on flag[dir][row>>5] >= 8 once per 32 steps.
__global__ __launch_bounds__(768, 1) void fused_k(
    const float* __restrict__ packed,
    const float* __restrict__ Wxf, const float* __restrict__ bf,
    const float* __restrict__ Wxb, const float* __restrict__ bb,
    float* __restrict__ Xf, float* __restrict__ Xb,
    const float* __restrict__ Whf, const float* __restrict__ Whb,
    float* __restrict__ enc, ull* __restrict__ pairsE, ull* __restrict__ pairsD,
    float* __restrict__ c0, int* __restrict__ xflags) {
    __shared__ float pAs[8][36];
    __shared__ float pBs[8][392];
    __shared__ float h_s[768];
    __shared__ float gbuf[48];
    __shared__ float xs[48];
    const int tid = threadIdx.x;

    if (blockIdx.x >= 128) {
        // ---------------- producer role ----------------
        const int p = blockIdx.x - 128;
        const int pass = p >> 4;
        const int dirsel = (p >> 3) & 1;
        const int tc = p & 7;
        const int band = dirsel ? (7 - pass) : pass;
        const float* B = dirsel ? Wxb : Wxf;
        const float* bias = dirsel ? bb : bf;
        float* C = dirsel ? Xb : Xf;
        const int n0 = tc * 384;
        const int qg = tc >> 1;          // gate group (tile-uniform)
        const int ty = tid / 48, tx = tid % 48;  // 16 x 48
        for (int s = 0; s < 4; ++s) {
            const int sm0 = band * 128 + (dirsel ? (3 - s) : s) * 32;
            float acc[2][8] = {};
            for (int k0 = 0; k0 < FE_; k0 += 8) {
                float4 av = make_float4(0.f, 0.f, 0.f, 0.f);
                if (tid < 64)
                    av = *(const float4*)(packed + (size_t)(sm0 + (tid >> 1)) * FE_ + k0 + (tid & 1) * 4);
                float4 bv = *(const float4*)(B + (size_t)(k0 + tid / 96) * G4_ + n0 + (tid % 96) * 4);
                __syncthreads();
                if (tid < 64) {
                    pAs[(tid & 1) * 4 + 0][tid >> 1] = av.x;
                    pAs[(tid & 1) * 4 + 1][tid >> 1] = av.y;
                    pAs[(tid & 1) * 4 + 2][tid >> 1] = av.z;
                    pAs[(tid & 1) * 4 + 3][tid >> 1] = av.w;
                }
                *(float4*)&pBs[tid / 96][(tid % 96) * 4] = bv;
                __syncthreads();
                #pragma unroll
                for (int kk = 0; kk < 8; ++kk) {
                    float a0 = pAs[kk][ty * 2], a1 = pAs[kk][ty * 2 + 1];
                    float b8[8];
                    *(float4*)&b8[0] = *(const float4*)&pBs[kk][tx * 8];
                    *(float4*)&b8[4] = *(const float4*)&pBs[kk][tx * 8 + 4];
                    #pragma unroll
                    for (int j = 0; j < 8; ++j) {
                        acc[0][j] += a0 * b8[j];
                        acc[1][j] += a1 * b8[j];
                    }
                }
            }
            #pragma unroll
            for (int i = 0; i < 2; ++i) {
                const int row = sm0 + ty * 2 + i;
                #pragma unroll
                for (int j = 0; j < 8; ++j) {
                    const int ncol = n0 + tx * 8 + j;
                    const int jc = ncol - qg * H_;
                    const int nsw = (jc / 12) * 48 + (jc % 12) * 4 + qg;
                    st_agent_f(&C[(size_t)row * G4_ + nsw], acc[i][j] + bias[ncol]);
                }
            }
            __syncthreads();   // drain all threads' stores before flag
            if (tid == 0)
                __hip_atomic_fetch_add(&xflags[dirsel * 32 + (sm0 >> 5)], 1,
                                       __ATOMIC_RELEASE, __HIP_MEMORY_SCOPE_AGENT);
        }
        return;
    }

    // ---------------- encoder role (r2 structure verbatim) ----------------
    const int dir = blockIdx.x >> 6;
    const int wb  = blockIdx.x & 63;
    const float* X  = dir ? Xb : Xf;
    const float* Wh = dir ? Whb : Whf;
    ull* pp = pairsE + (size_t)dir * 1536;   // [2par][768]
    const int out = tid >> 4, kl = tid & 15;
    const int q = out / 12, jj = out - q * 12;
    const int col = q * H_ + wb * 12 + jj;

    float w[12][4];
    #pragma unroll
    for (int i = 0; i < 12; ++i) {
        int kb = kl * 4 + 64 * i;
        #pragma unroll
        for (int e = 0; e < 4; ++e)
            w[i][e] = Wh[(size_t)(kb + e) * G4_ + col];
    }

    float c = 0.f;
    for (int t = 0; t < SEQ_; ++t) {
        const int row = dir ? (SEQ_ - 1 - t) : t;
        if ((t & 31) == 0) {   // gate on X 32-row block availability
            if (tid == 0) {
                const int rb = row >> 5;
                while (__hip_atomic_load(&xflags[dir * 32 + rb], __ATOMIC_ACQUIRE,
                                         __HIP_MEMORY_SCOPE_AGENT) < 8) {}
            }
            __syncthreads();
        }
        float xv = 0.f;
        if (tid < 48) xv = X[(size_t)row * G4_ + wb * 48 + tid];  // swizzled, prefetch

        ull* pr = pp + (size_t)(t & 1) * 768 + tid;
        ull v = ld_agent(pr);
        while ((unsigned)(v >> 32) != (unsigned)t) v = ld_agent(pr);
        h_s[tid] = __uint_as_float((unsigned)v);
        __syncthreads();                                  // A: h_s ready

        float s = 0.f;
        #pragma unroll
        for (int i = 0; i < 12; ++i) {
            const float4 hv = *(const float4*)&h_s[kl * 4 + 64 * i];
            s += w[i][0] * hv.x + w[i][1] * hv.y + w[i][2] * hv.z + w[i][3] * hv.w;
        }
        s += __shfl_xor(s, 1); s += __shfl_xor(s, 2);
        s += __shfl_xor(s, 4); s += __shfl_xor(s, 8);
        if (kl == 0) gbuf[out] = s;
        if (tid < 48) xs[tid] = xv;
        __syncthreads();                                  // B: gbuf/xs ready

        if (tid < 12) {
            // xs order (swizzled): jj*4 + gate
            float iv = gbuf[tid]      + xs[4 * tid + 0];
            float fv = gbuf[12 + tid] + xs[4 * tid + 1];
            float gv = gbuf[24 + tid] + xs[4 * tid + 2];
            float ov = gbuf[36 + tid] + xs[4 * tid + 3];
            c = sigf(fv) * c + sigf(iv) * tanhf(gv);
            float h = sigf(ov) * tanhf(c);
            int jg = wb * 12 + tid;
            enc[(size_t)row * H2_ + dir * H_ + jg] = h;
            ull pk = ((ull)(unsigned)(t + 1) << 32) | (ull)__float_as_uint(h);
            st_agent(pp + (size_t)((t + 1) & 1) * 768 + jg, pk);
            if (t == SEQ_ - 1) {
                st_agent(pairsD + (size_t)(dir * H_ + jg), (ull)__float_as_uint(h));
                c0[dir * H_ + jg] = c;
            }
        }
        // no extra barrier needed (r2-proven: reads of h_s/gbuf/xs precede B;
        // step-t+1 writes follow A(t+1)/B(t+1))
    }
}

// ---------------- persistent decoder LSTM (proven r6-r8 verbatim) ----------------
__global__ __launch_bounds__(768, 1) void lstm_dec_k(
    const float* __restrict__ Xd, const float* __restrict__ Wh,
    float* __restrict__ Hn, ull* __restrict__ pairs,
    const float* __restrict__ c0) {
    const int wb = blockIdx.x;
    const int tid = threadIdx.x;
    const int w = tid >> 6, lane = tid & 63;
    const int g16 = lane >> 4;
    const int jg = wb * 12 + w;
    const int d = lane >> 2, q = lane & 3;

    float wgt[6][4][4];
    #pragma unroll
    for (int i = 0; i < 6; ++i)
        #pragma unroll
        for (int e = 0; e < 4; ++e) {
            int k = 4 * lane + e + 256 * i;
            #pragma unroll
            for (int g = 0; g < 4; ++g)
                wgt[i][e][g] = Wh[(size_t)k * G8_ + g * H2_ + jg];
        }
    #pragma unroll
    for (int i = 0; i < 6; ++i)
        #pragma unroll
        for (int e = 0; e < 4; ++e)
            #pragma unroll
            for (int g = 0; g < 4; ++g)
                asm volatile("" : "+v"(wgt[i][e][g]));

    __shared__ float h_s[2][1536];
    __shared__ float part[4][64];
    float c = (w == 0 && lane < 48) ? c0[wb * 12 + d] : 0.f;

    for (int t = 0; t < T_; ++t) {
        float xq = 0.f;
        if (w == 0 && lane < 48) xq = Xd[(size_t)t * G8_ + wb * 48 + lane];

        const int par = t & 1;
        ull* p0 = pairs + (size_t)par * 1536 + tid;
        ull* p1 = p0 + 768;
        ull v0 = ld_agent(p0);
        while ((unsigned)(v0 >> 32) != (unsigned)t) v0 = ld_agent(p0);
        ull v1 = ld_agent(p1);
        while ((unsigned)(v1 >> 32) != (unsigned)t) v1 = ld_agent(p1);
        h_s[par][tid]       = __uint_as_float((unsigned)v0);
        h_s[par][tid + 768] = __uint_as_float((unsigned)v1);
        __syncthreads();                                   // A

        float a0 = 0.f, a1 = 0.f, a2 = 0.f, a3 = 0.f;
        #pragma unroll
        for (int i = 0; i < 6; ++i) {
            const float4 hv = *(const float4*)&h_s[par][4 * lane + 256 * i];
            a0 += wgt[i][0][0] * hv.x + wgt[i][1][0] * hv.y + wgt[i][2][0] * hv.z + wgt[i][3][0] * hv.w;
            a1 += wgt[i][0][1] * hv.x + wgt[i][1][1] * hv.y + wgt[i][2][1] * hv.z + wgt[i][3][1] * hv.w;
            a2 += wgt[i][0][2] * hv.x + wgt[i][1][2] * hv.y + wgt[i][2][2] * hv.z + wgt[i][3][2] * hv.w;
            a3 += wgt[i][0][3] * hv.x + wgt[i][1][3] * hv.y + wgt[i][2][3] * hv.z + wgt[i][3][3] * hv.w;
        }
        #pragma unroll
        for (int m = 1; m < 16; m <<= 1) {
            a0 += __shfl_xor(a0, m); a1 += __shfl_xor(a1, m);
            a2 += __shfl_xor(a2, m); a3 += __shfl_xor(a3, m);
        }
        if ((lane & 15) == 0)
            *(float4*)&part[g16][w * 4] = make_float4(a0, a1, a2, a3);
        __syncthreads();                                   // B

        if (w == 0) {
            float s = part[0][lane] + part[1][lane] + part[2][lane] + part[3][lane] + xq;
            float tr = (q == 2) ? tanhf(s) : sigf(s);
            float s1 = __shfl_xor(tr, 1), s2 = __shfl_xor(tr, 2), s3 = __shfl_xor(tr, 3);
            float I  = (q == 0) ? tr : (q == 1) ? s1 : (q == 2) ? s2 : s3;
            float Fv = (q == 0) ? s1 : (q == 1) ? tr : (q == 2) ? s3 : s2;
            float G  = (q == 0) ? s2 : (q == 1) ? s3 : (q == 2) ? tr : s1;
            float O  = (q == 0) ? s3 : (q == 1) ? s2 : (q == 2) ? s1 : tr;
            c = Fv * c + I * G;
            float h = O * tanhf(c);
            float hc = __shfl(h, lane * 4);
            if (lane < 12) {
                Hn[(size_t)t * H2_ + wb * 12 + lane] = hc;
                ull pk = ((ull)(unsigned)(t + 1) << 32) | (ull)__float_as_uint(hc);
                st_agent(pairs + (size_t)((t + 1) & 1) * 1536 + wb * 12 + lane, pk);
            }
        }
    }
}

// ---------------- scores: out[t][a] = Amat[t] . enc[t*32+a] ----------------
__global__ void score_k(const float* __restrict__ Amat, const float* __restrict__ enc,
                        float* __restrict__ outp) {
    int t = blockIdx.x, tid = threadIdx.x;
    __shared__ float a_s[H2_];
    for (int i = tid; i < H2_; i += 256) a_s[i] = Amat[(size_t)t * H2_ + i];
    __syncthreads();
    int aa = tid >> 3, p = tid & 7;
    const float4* e = (const float4*)(enc + (size_t)(t * A_ + aa) * H2_ + p * 192);
    const float4* ap = (const float4*)(a_s + p * 192);
    float s = 0.f;
    #pragma unroll
    for (int i = 0; i < 48; ++i) {
        float4 av = ap[i], ev = e[i];
        s += av.x * ev.x + av.y * ev.y + av.z * ev.z + av.w * ev.w;
    }
    s += __shfl_xor(s, 1); s += __shfl_xor(s, 2); s += __shfl_xor(s, 4);
    if (p == 0) outp[t * A_ + aa] = s;
}

// ---------------- host launch ----------------
extern "C" void kernel_launch(void* const* d_in, const int* in_sizes, int n_in,
                              void* d_out, int out_size, void* d_ws, size_t ws_size,
                              hipStream_t stream) {
    const int*   lattice = (const int*)d_in[0];
    const int*   inputs  = (const int*)d_in[2];
    const int*   gold    = (const int*)d_in[4];
    const int*   sos     = (const int*)d_in[5];
    const float* emb     = (const float*)d_in[6];
    const float* tok     = (const float*)d_in[7];
    const float* Wxf = (const float*)d_in[8];
    const float* Whf = (const float*)d_in[9];
    const float* bf  = (const float*)d_in[10];
    const float* Wxb = (const float*)d_in[11];
    const float* Whb = (const float*)d_in[12];
    const float* bb  = (const float*)d_in[13];
    const float* dWx = (const float*)d_in[14];
    const float* dWh = (const float*)d_in[15];
    const float* db  = (const float*)d_in[16];
    const float* aW  = (const float*)d_in[17];
    float* ws  = (float*)d_ws;
    float* out = (float*)d_out;

    float* packed = ws + OFF_PACKED;
    float* Xf     = ws + OFF_XF;
    float* Xb     = ws + OFF_XB;
    float* Xd     = ws + OFF_XD;
    float* xdin   = ws + OFF_XDIN;
    float* enc    = ws + OFF_ENC;
    float* Hn     = ws + OFF_HN;
    float* Amat   = ws + OFF_AMAT;
    float* c0     = ws + OFF_C0;
    int*   xflags = (int*)(ws + OFF_XFLAGS);
    ull*   pairsE = (ull*)(ws + OFF_PAIRS_E);
    ull*   pairsD = (ull*)(ws + OFF_PAIRS_D);

    // reset flags + pair tags (graph-replay safe; {tag=0,val=0} == h0 state)
    hipMemsetAsync((char*)d_ws + OFF_XFLAGS * sizeof(float), 0, MEMSET_BYTES, stream);

    embed_k<<<SEQ_ + T_, 256, 0, stream>>>(lattice, inputs, gold, sos, emb, tok,
                                           packed, xdin);
    // small decoder-input GEMM first (doesn't block the fused pipeline long)
    gemm_bias_k<<<dim3(G8_ / BN, 1), 256, 0, stream>>>(xdin, dWx, db, Xd,
                                                       T_, G8_, DDEC_, H2_, 12);
    // fused: encoder (blocks 0-127) + Xf/Xb GEMM producers (blocks 128-255)
    fused_k<<<256, 768, 0, stream>>>(packed, Wxf, bf, Wxb, bb, Xf, Xb,
                                     Whf, Whb, enc, pairsE, pairsD, c0, xflags);
    lstm_dec_k<<<128, 768, 0, stream>>>(Xd, dWh, Hn, pairsD, c0);
    gemm_bias_k<<<dim3(H2_ / BN, 1), 256, 0, stream>>>(Hn, aW, nullptr, Amat,
                                                       T_, H2_, H2_, 0, 1);
    score_k<<<T_, 256, 0, stream>>>(Amat, enc, out);
}

// Round 10
// 3239.183 us; speedup vs baseline: 1.7122x; 1.1995x over previous
//
#include <hip/hip_runtime.h>
#include <cstddef>
#include <cstdint>

// ---------------- problem dims ----------------
#define T_ 32
#define A_ 32
#define F_ 4
#define E_ 256
#define FE_ 1024
#define H_ 768
#define H2_ 1536
#define G4_ 3072     // 4*H
#define G8_ 6144     // 4*H2
#define DTOK_ 256
#define DDEC_ 1280
#define SEQ_ 1024    // T*A

typedef unsigned long long ull;

// ---------------- ws layout (float offsets) ----------------
constexpr size_t OFF_PACKED  = 0;                          // 1024*1024
constexpr size_t OFF_XF      = OFF_PACKED + 1024ull*1024;  // 1024*3072 (swizzled n'=4j+q)
constexpr size_t OFF_XB      = OFF_XF + 1024ull*3072;
constexpr size_t OFF_XDIN    = OFF_XB + 1024ull*3072;      // 32*1280
constexpr size_t OFF_ENC     = OFF_XDIN + 32*1280;         // 1024*1536
constexpr size_t OFF_HN      = OFF_ENC + 1024ull*1536;     // 32*1536
constexpr size_t OFF_AMAT    = OFF_HN + 32*1536;           // 32*1536
constexpr size_t OFF_C0      = OFF_AMAT + 32*1536;         // 1536
constexpr size_t OFF_XFLAGS  = OFF_C0 + 1536;              // 64 ints [dir][rc32]
constexpr size_t OFF_PAIRS_E = OFF_XFLAGS + 64;            // [dir][par][768] u64 = 6144 f
constexpr size_t OFF_PAIRS_D = OFF_PAIRS_E + 6144;         // [par][1536] u64 = 6144 f
constexpr size_t MEMSET_BYTES = (64 + 6144 + 6144) * 4;

__device__ __forceinline__ float sigf(float x) { return 1.f / (1.f + __expf(-x)); }

__device__ __forceinline__ ull ld_agent(const ull* p) {
    return __hip_atomic_load(p, __ATOMIC_RELAXED, __HIP_MEMORY_SCOPE_AGENT);
}
__device__ __forceinline__ void st_agent(ull* p, ull v) {
    __hip_atomic_store(p, v, __ATOMIC_RELAXED, __HIP_MEMORY_SCOPE_AGENT);
}
__device__ __forceinline__ void st_agent_rel(ull* p, ull v) {
    __hip_atomic_store(p, v, __ATOMIC_RELEASE, __HIP_MEMORY_SCOPE_AGENT);
}
__device__ __forceinline__ void st_agent_f(float* p, float v) {
    __hip_atomic_store(p, v, __ATOMIC_RELAXED, __HIP_MEMORY_SCOPE_AGENT);
}
__device__ __forceinline__ float ld_agent_f(const float* p) {
    return __hip_atomic_load(p, __ATOMIC_RELAXED, __HIP_MEMORY_SCOPE_AGENT);
}
__device__ __forceinline__ int xsw(int e) { return e ^ (((e >> 5) & 7) << 2); }

// ---------------- embed + decoder-input gather ----------------
__global__ void embed_k(const int* __restrict__ lattice, const int* __restrict__ inputs,
                        const int* __restrict__ gold, const int* __restrict__ sos,
                        const float* __restrict__ emb, const float* __restrict__ tok_emb,
                        float* __restrict__ packed, float* __restrict__ xdec_in) {
    int b = blockIdx.x, tid = threadIdx.x;
    if (b < SEQ_) {
        #pragma unroll
        for (int f = 0; f < F_; ++f) {
            int vid = lattice[b * F_ + f];
            packed[(size_t)b * FE_ + f * E_ + tid] = emb[(size_t)vid * E_ + tid];
        }
    } else {
        int t = b - SEQ_;  // 0..31
        for (int j = tid; j < DDEC_; j += 256) {
            float v;
            if (j < FE_) {
                int f = j >> 8, e2 = j & 255;
                int vid = (t == 0) ? sos[f]
                                   : lattice[(((t - 1) * A_) + gold[t - 1]) * F_ + f];
                v = emb[(size_t)vid * E_ + e2];
            } else {
                v = tok_emb[(size_t)inputs[t] * DTOK_ + (j - FE_)];
            }
            xdec_in[(size_t)t * DDEC_ + j] = v;
        }
    }
}

// ---------------- fp32 tiled GEMM (Amat only) ----------------
#define BM 128
#define BN 128
#define BK 8
__global__ __launch_bounds__(256) void gemm_bias_k(
    const float* __restrict__ A, const float* __restrict__ B,
    const float* __restrict__ bias, float* __restrict__ C,
    int M, int N, int K) {
    __shared__ float As[BK][BM + 4];
    __shared__ float Bs[BK][BN + 4];
    int tid = threadIdx.x;
    int n0 = blockIdx.x * BN, m0 = blockIdx.y * BM;
    int tx = tid & 15, ty = tid >> 4;
    int lam = tid >> 1, lak = (tid & 1) * 4;
    int lbk = tid >> 5, lbn = (tid & 31) * 4;
    float acc[8][8] = {};
    for (int k0 = 0; k0 < K; k0 += BK) {
        float4 av = make_float4(0.f, 0.f, 0.f, 0.f);
        if (m0 + lam < M)
            av = *(const float4*)(A + (size_t)(m0 + lam) * K + k0 + lak);
        float4 bv = *(const float4*)(B + (size_t)(k0 + lbk) * N + n0 + lbn);
        __syncthreads();
        As[lak + 0][lam] = av.x; As[lak + 1][lam] = av.y;
        As[lak + 2][lam] = av.z; As[lak + 3][lam] = av.w;
        *(float4*)&Bs[lbk][lbn] = bv;
        __syncthreads();
        #pragma unroll
        for (int kk = 0; kk < BK; ++kk) {
            float a[8], b[8];
            *(float4*)&a[0] = *(const float4*)&As[kk][ty * 8];
            *(float4*)&a[4] = *(const float4*)&As[kk][ty * 8 + 4];
            *(float4*)&b[0] = *(const float4*)&Bs[kk][tx * 8];
            *(float4*)&b[4] = *(const float4*)&Bs[kk][tx * 8 + 4];
            #pragma unroll
            for (int i = 0; i < 8; ++i)
                #pragma unroll
                for (int j = 0; j < 8; ++j)
                    acc[i][j] += a[i] * b[j];
        }
    }
    #pragma unroll
    for (int i = 0; i < 8; ++i) {
        int m = m0 + ty * 8 + i;
        if (m >= M) break;
        #pragma unroll
        for (int j = 0; j < 8; ++j) {
            int n = n0 + tx * 8 + j;
            float bb = bias ? bias[n] : 0.f;
            C[(size_t)m * N + n] = acc[i][j] + bb;
        }
    }
}

// ================= fused: encoder + {X-producer -> decoder} =================
// 256 blocks x 768 threads (1/CU). Blocks [0,128): r2-structure encoder.
// Blocks [128,256): pid: produce one 32-row x half-col X chunk (coalesced
// agent stores via LDS stage), then compute own Xd slice in LDS, then run
// the decoder for dims [pid*12, pid*12+12).
__global__ __launch_bounds__(768, 1) void fused_k(
    const float* __restrict__ packed,
    const float* __restrict__ Wxf, const float* __restrict__ bf,
    const float* __restrict__ Wxb, const float* __restrict__ bb,
    float* __restrict__ Xf, float* __restrict__ Xb,
    const float* __restrict__ Whf, const float* __restrict__ Whb,
    float* __restrict__ enc, ull* __restrict__ pairsE, ull* __restrict__ pairsD,
    float* __restrict__ c0, int* __restrict__ xflags,
    const float* __restrict__ xdin, const float* __restrict__ dWx,
    const float* __restrict__ db, const float* __restrict__ dWh,
    float* __restrict__ Hn) {
    __shared__ float smem[13056];   // 52.2 KB, role-aliased
    const int tid = threadIdx.x;

    if (blockIdx.x >= 128) {
        // ======== producer role ========
        const int pid  = blockIdx.x - 128;       // 0..127
        const int pdir = pid >> 6;
        const int q6   = pid & 63;
        const int rc32 = q6 >> 1;                // 32-row chunk
        const int ch   = q6 & 1;                 // hidden half
        const float* Wx = pdir ? Wxb : Wxf;
        const float* bs = pdir ? bb : bf;
        float* Xc = pdir ? Xb : Xf;
        const int R0 = rc32 * 32;
        const int Hbase = ch * 384;
        const int rgrp = tid / 192;              // wave-uniform
        const int cgrp = tid % 192;
        float* Bld = smem;                       // [4][1568]
        float* stg = smem + 4 * 1568;            // [4][1536]

        float4 bias4[2];
        #pragma unroll
        for (int cc = 0; cc < 2; ++cc) {
            int hc = Hbase + 2 * cgrp + cc;
            bias4[cc] = make_float4(bs[0 * H_ + hc], bs[1 * H_ + hc],
                                    bs[2 * H_ + hc], bs[3 * H_ + hc]);
        }
        float4 acc[8][2] = {};

        for (int k0 = 0; k0 < FE_; k0 += 4) {
            float4 bl[2];
            int kkq[2], gq[2], uq[2];
            #pragma unroll
            for (int b = 0; b < 2; ++b) {
                int qi = tid + 768 * b;
                kkq[b] = qi / 384; int rest = qi % 384;
                gq[b] = rest / 96; uq[b] = rest % 96;
                bl[b] = *(const float4*)(Wx + (size_t)(k0 + kkq[b]) * G4_ +
                                         gq[b] * H_ + Hbase + 4 * uq[b]);
            }
            float4 av[8];
            #pragma unroll
            for (int i = 0; i < 8; ++i)
                av[i] = *(const float4*)(packed + (size_t)(R0 + rgrp * 8 + i) * FE_ + k0);
            __syncthreads();   // prev-chunk Bld reads done
            #pragma unroll
            for (int b = 0; b < 2; ++b) {
                float vv[4] = {bl[b].x, bl[b].y, bl[b].z, bl[b].w};
                #pragma unroll
                for (int jj = 0; jj < 4; ++jj) {
                    int e = 16 * uq[b] + 4 * jj + gq[b];
                    Bld[kkq[b] * 1568 + xsw(e)] = vv[jj];
                }
            }
            __syncthreads();   // Bld ready
            #pragma unroll
            for (int kk = 0; kk < 4; ++kk) {
                int q40 = 8 * cgrp;
                float4 b0 = *(const float4*)&Bld[kk * 1568 + xsw(q40)];
                float4 b1 = *(const float4*)&Bld[kk * 1568 + xsw(q40 + 4)];
                #pragma unroll
                for (int i = 0; i < 8; ++i) {
                    float a = (kk == 0) ? av[i].x : (kk == 1) ? av[i].y
                            : (kk == 2) ? av[i].z : av[i].w;
                    acc[i][0].x += a * b0.x; acc[i][0].y += a * b0.y;
                    acc[i][0].z += a * b0.z; acc[i][0].w += a * b0.w;
                    acc[i][1].x += a * b1.x; acc[i][1].y += a * b1.y;
                    acc[i][1].z += a * b1.z; acc[i][1].w += a * b1.w;
                }
            }
        }
        // stage + coalesced agent stores, 8 passes of 4 rows
        for (int p = 0; p < 8; ++p) {
            if (rgrp == (p >> 1)) {
                #pragma unroll
                for (int ii = 0; ii < 4; ++ii) {
                    int i = (p & 1) * 4 + ii;
                    #pragma unroll
                    for (int cc = 0; cc < 2; ++cc) {
                        int q4 = 8 * cgrp + 4 * cc;
                        float4 v = acc[i][cc];
                        float4 bsv = bias4[cc];
                        v.x += bsv.x; v.y += bsv.y; v.z += bsv.z; v.w += bsv.w;
                        *(float4*)&stg[ii * 1536 + xsw(q4)] = v;
                    }
                }
            }
            __syncthreads();
            #pragma unroll
            for (int j = 0; j < 8; ++j) {
                int x = tid + 768 * j;
                int rr = x / 1536, e = x % 1536;
                st_agent_f(&Xc[(size_t)(R0 + 4 * p + rr) * G4_ + ch * 1536 + e],
                           stg[rr * 1536 + xsw(e)]);
            }
            __syncthreads();
        }
        if (tid == 0)
            __hip_atomic_fetch_add(&xflags[pdir * 32 + rc32], 1,
                                   __ATOMIC_RELEASE, __HIP_MEMORY_SCOPE_AGENT);

        // ======== decoder role (block wb = pid) ========
        const int wb = pid;
        const int w = tid >> 6, lane = tid & 63;
        const int g16 = lane >> 4;
        const int jg = wb * 12 + w;
        const int d = lane >> 2, q = lane & 3;
        float* hs2 = smem;            // [2][1536]
        float* part = smem + 3072;    // [4][64]
        float* xds = smem + 3328;     // [32][48]
        __syncthreads();              // producer smem use finished

        // Xd slice: xds[t][cl] = xdin[t] . dWx[:, gcol] + db[gcol]
        #pragma unroll
        for (int b = 0; b < 2; ++b) {
            int v = tid + 768 * b;            // 0..1535
            int t = v / 48, cl = v % 48;
            int dd = cl >> 2, gg = cl & 3;
            int gcol = gg * H2_ + wb * 12 + dd;
            float s = db[gcol];
            const float* xr = xdin + (size_t)t * DDEC_;
            for (int k = 0; k < DDEC_; k += 4) {
                float4 xv = *(const float4*)&xr[k];
                s += xv.x * dWx[(size_t)(k + 0) * G8_ + gcol];
                s += xv.y * dWx[(size_t)(k + 1) * G8_ + gcol];
                s += xv.z * dWx[(size_t)(k + 2) * G8_ + gcol];
                s += xv.w * dWx[(size_t)(k + 3) * G8_ + gcol];
            }
            xds[v] = s;
        }

        float wgt[6][4][4];
        #pragma unroll
        for (int i = 0; i < 6; ++i)
            #pragma unroll
            for (int e = 0; e < 4; ++e) {
                int k = 4 * lane + e + 256 * i;
                #pragma unroll
                for (int g = 0; g < 4; ++g)
                    wgt[i][e][g] = dWh[(size_t)k * G8_ + g * H2_ + jg];
            }
        #pragma unroll
        for (int i = 0; i < 6; ++i)
            #pragma unroll
            for (int e = 0; e < 4; ++e)
                #pragma unroll
                for (int g = 0; g < 4; ++g)
                    asm volatile("" : "+v"(wgt[i][e][g]));
        __syncthreads();              // xds ready

        float c = 0.f;
        for (int t = 0; t < T_; ++t) {
            // tags offset +1: seed tag = 1 (memset-0 never matches)
            const int par = t & 1;
            ull* p0 = pairsD + (size_t)par * 1536 + tid;
            ull* p1 = p0 + 768;
            ull v0 = ld_agent(p0);
            while ((unsigned)(v0 >> 32) != (unsigned)(t + 1)) v0 = ld_agent(p0);
            ull v1 = ld_agent(p1);
            while ((unsigned)(v1 >> 32) != (unsigned)(t + 1)) v1 = ld_agent(p1);
            hs2[par * 1536 + tid]       = __uint_as_float((unsigned)v0);
            hs2[par * 1536 + tid + 768] = __uint_as_float((unsigned)v1);
            __syncthreads();
            if (t == 0 && w == 0 && lane < 48)
                c = ld_agent_f(&c0[wb * 12 + d]);

            float a0 = 0.f, a1 = 0.f, a2 = 0.f, a3 = 0.f;
            #pragma unroll
            for (int i = 0; i < 6; ++i) {
                const float4 hv = *(const float4*)&hs2[par * 1536 + 4 * lane + 256 * i];
                a0 += wgt[i][0][0] * hv.x + wgt[i][1][0] * hv.y + wgt[i][2][0] * hv.z + wgt[i][3][0] * hv.w;
                a1 += wgt[i][0][1] * hv.x + wgt[i][1][1] * hv.y + wgt[i][2][1] * hv.z + wgt[i][3][1] * hv.w;
                a2 += wgt[i][0][2] * hv.x + wgt[i][1][2] * hv.y + wgt[i][2][2] * hv.z + wgt[i][3][2] * hv.w;
                a3 += wgt[i][0][3] * hv.x + wgt[i][1][3] * hv.y + wgt[i][2][3] * hv.z + wgt[i][3][3] * hv.w;
            }
            #pragma unroll
            for (int m = 1; m < 16; m <<= 1) {
                a0 += __shfl_xor(a0, m); a1 += __shfl_xor(a1, m);
                a2 += __shfl_xor(a2, m); a3 += __shfl_xor(a3, m);
            }
            if ((lane & 15) == 0)
                *(float4*)&part[g16 * 64 + w * 4] = make_float4(a0, a1, a2, a3);
            __syncthreads();

            if (w == 0) {
                float s = part[0 * 64 + lane] + part[1 * 64 + lane]
                        + part[2 * 64 + lane] + part[3 * 64 + lane] + xds[t * 48 + lane];
                float tr = (q == 2) ? tanhf(s) : sigf(s);
                float s1 = __shfl_xor(tr, 1), s2 = __shfl_xor(tr, 2), s3 = __shfl_xor(tr, 3);
                float I  = (q == 0) ? tr : (q == 1) ? s1 : (q == 2) ? s2 : s3;
                float Fv = (q == 0) ? s1 : (q == 1) ? tr : (q == 2) ? s3 : s2;
                float G  = (q == 0) ? s2 : (q == 1) ? s3 : (q == 2) ? tr : s1;
                float O  = (q == 0) ? s3 : (q == 1) ? s2 : (q == 2) ? s1 : tr;
                c = Fv * c + I * G;
                float h = O * tanhf(c);
                float hc = __shfl(h, lane * 4);
                if (lane < 12) {
                    Hn[(size_t)t * H2_ + wb * 12 + lane] = hc;
                    ull pk = ((ull)(unsigned)(t + 2) << 32) | (ull)__float_as_uint(hc);
                    st_agent(pairsD + (size_t)((t + 1) & 1) * 1536 + wb * 12 + lane, pk);
                }
            }
        }
        return;
    }

    // ======== encoder role (r2 structure, proven) ========
    const int dir = blockIdx.x >> 6;
    const int wb  = blockIdx.x & 63;
    const float* X  = dir ? Xb : Xf;
    const float* Wh = dir ? Whb : Whf;
    ull* pp = pairsE + (size_t)dir * 1536;   // [2par][768]
    const int out = tid >> 4, kl = tid & 15;
    const int q = out / 12, jj = out - q * 12;
    const int col = q * H_ + wb * 12 + jj;
    float* h_s = smem;            // [768]
    float* gbuf = smem + 768;     // [48]
    float* xs = smem + 816;       // [48]

    float w[12][4];
    #pragma unroll
    for (int i = 0; i < 12; ++i) {
        int kb = kl * 4 + 64 * i;
        #pragma unroll
        for (int e = 0; e < 4; ++e)
            w[i][e] = Wh[(size_t)(kb + e) * G4_ + col];
    }

    float c = 0.f;
    for (int t = 0; t < SEQ_; ++t) {
        const int row = dir ? (SEQ_ - 1 - t) : t;
        if ((t & 31) == 0) {   // gate on 32-row X chunk (2 half-col producers)
            if (tid == 0) {
                const int rb = row >> 5;
                while (__hip_atomic_load(&xflags[dir * 32 + rb], __ATOMIC_ACQUIRE,
                                         __HIP_MEMORY_SCOPE_AGENT) < 2) {}
            }
            __syncthreads();
        }
        float xv = 0.f;
        if (tid < 48) xv = X[(size_t)row * G4_ + wb * 48 + tid];

        ull* pr = pp + (size_t)(t & 1) * 768 + tid;
        ull v = ld_agent(pr);
        while ((unsigned)(v >> 32) != (unsigned)t) v = ld_agent(pr);
        h_s[tid] = __uint_as_float((unsigned)v);
        __syncthreads();                                  // A: h_s ready

        float s = 0.f;
        #pragma unroll
        for (int i = 0; i < 12; ++i) {
            const float4 hv = *(const float4*)&h_s[kl * 4 + 64 * i];
            s += w[i][0] * hv.x + w[i][1] * hv.y + w[i][2] * hv.z + w[i][3] * hv.w;
        }
        s += __shfl_xor(s, 1); s += __shfl_xor(s, 2);
        s += __shfl_xor(s, 4); s += __shfl_xor(s, 8);
        if (kl == 0) gbuf[out] = s;
        if (tid < 48) xs[tid] = xv;
        __syncthreads();                                  // B: gbuf/xs ready

        if (tid < 12) {
            float iv = gbuf[tid]      + xs[4 * tid + 0];
            float fv = gbuf[12 + tid] + xs[4 * tid + 1];
            float gv = gbuf[24 + tid] + xs[4 * tid + 2];
            float ov = gbuf[36 + tid] + xs[4 * tid + 3];
            c = sigf(fv) * c + sigf(iv) * tanhf(gv);
            float h = sigf(ov) * tanhf(c);
            int jg = wb * 12 + tid;
            enc[(size_t)row * H2_ + dir * H_ + jg] = h;
            ull pk = ((ull)(unsigned)(t + 1) << 32) | (ull)__float_as_uint(h);
            st_agent(pp + (size_t)((t + 1) & 1) * 768 + jg, pk);
            if (t == SEQ_ - 1) {
                st_agent_f(&c0[dir * H_ + jg], c);
                ull pk0 = (1ull << 32) | (ull)__float_as_uint(h);
                st_agent_rel(pairsD + (size_t)(dir * H_ + jg), pk0);  // seed tag 1
            }
        }
    }
}

// ---------------- scores: out[t][a] = Amat[t] . enc[t*32+a] ----------------
__global__ void score_k(const float* __restrict__ Amat, const float* __restrict__ enc,
                        float* __restrict__ outp) {
    int t = blockIdx.x, tid = threadIdx.x;
    __shared__ float a_s[H2_];
    for (int i = tid; i < H2_; i += 256) a_s[i] = Amat[(size_t)t * H2_ + i];
    __syncthreads();
    int aa = tid >> 3, p = tid & 7;
    const float4* e = (const float4*)(enc + (size_t)(t * A_ + aa) * H2_ + p * 192);
    const float4* ap = (const float4*)(a_s + p * 192);
    float s = 0.f;
    #pragma unroll
    for (int i = 0; i < 48; ++i) {
        float4 av = ap[i], ev = e[i];
        s += av.x * ev.x + av.y * ev.y + av.z * ev.z + av.w * ev.w;
    }
    s += __shfl_xor(s, 1); s += __shfl_xor(s, 2); s += __shfl_xor(s, 4);
    if (p == 0) outp[t * A_ + aa] = s;
}

// ---------------- host launch ----------------
extern "C" void kernel_launch(void* const* d_in, const int* in_sizes, int n_in,
                              void* d_out, int out_size, void* d_ws, size_t ws_size,
                              hipStream_t stream) {
    const int*   lattice = (const int*)d_in[0];
    const int*   inputs  = (const int*)d_in[2];
    const int*   gold    = (const int*)d_in[4];
    const int*   sos     = (const int*)d_in[5];
    const float* emb     = (const float*)d_in[6];
    const float* tok     = (const float*)d_in[7];
    const float* Wxf = (const float*)d_in[8];
    const float* Whf = (const float*)d_in[9];
    const float* bf  = (const float*)d_in[10];
    const float* Wxb = (const float*)d_in[11];
    const float* Whb = (const float*)d_in[12];
    const float* bb  = (const float*)d_in[13];
    const float* dWx = (const float*)d_in[14];
    const float* dWh = (const float*)d_in[15];
    const float* db  = (const float*)d_in[16];
    const float* aW  = (const float*)d_in[17];
    float* ws  = (float*)d_ws;
    float* out = (float*)d_out;

    float* packed = ws + OFF_PACKED;
    float* Xf     = ws + OFF_XF;
    float* Xb     = ws + OFF_XB;
    float* xdin   = ws + OFF_XDIN;
    float* enc    = ws + OFF_ENC;
    float* Hn     = ws + OFF_HN;
    float* Amat   = ws + OFF_AMAT;
    float* c0     = ws + OFF_C0;
    int*   xflags = (int*)(ws + OFF_XFLAGS);
    ull*   pairsE = (ull*)(ws + OFF_PAIRS_E);
    ull*   pairsD = (ull*)(ws + OFF_PAIRS_D);

    // reset flags + pair tags (replay-safe; pairsE tag0 == h0 state; pairsD
    // waits tag>=1 so zeros never false-trigger)
    hipMemsetAsync((char*)d_ws + OFF_XFLAGS * sizeof(float), 0, MEMSET_BYTES, stream);

    embed_k<<<SEQ_ + T_, 256, 0, stream>>>(lattice, inputs, gold, sos, emb, tok,
                                           packed, xdin);
    fused_k<<<256, 768, 0, stream>>>(packed, Wxf, bf, Wxb, bb, Xf, Xb, Whf, Whb,
                                     enc, pairsE, pairsD, c0, xflags,
                                     xdin, dWx, db, dWh, Hn);
    gemm_bias_k<<<dim3(H2_ / BN, 1), 256, 0, stream>>>(Hn, aW, nullptr, Amat,
                                                       T_, H2_, H2_);
    score_k<<<T_, 256, 0, stream>>>(Amat, enc, out);
}